// Round 8
// baseline (1052.284 us; speedup 1.0000x reference)
//
// HierarchicalPattern — rev8. R7 post-mortem: mask kernel spent its time in
// (a) 256 block barriers (4 qi x 32 extract-iters x 2 syncthreads) and
// (b) cross-XCD L2 thrash (FETCH 172MB, WRITE 622MB: all 4 batches' gfT
// streamed through every XCD's 4MiB L2). Fix: (a) per-WAVE top-32 extraction
// (shuffle-only, no barriers) + parallel per-wave merge of 128 candidates;
// (b) XCD-pinned block mapping so batch b lives on XCDs {2b,2b+1}.
// I/O fp16 (confirmed R5); masked u16 = 0xFBFF (finite in fp16 and bf16).
#include <hip/hip_runtime.h>
#include <hip/hip_fp16.h>
#include <cstdint>

#define SEQ 4096
#define NB 4
#define DMODEL 1024
#define ID 64
#define LW 16
#define GK 32
#define TQ 4

#define NEG_INF (-__builtin_inff())
#define MASKED4 0xFBFFFBFFu

__device__ __forceinline__ float2 h2f2(unsigned int u) {
    __half2 h = *reinterpret_cast<__half2*>(&u);
    return __half22float2(h);
}

__device__ __forceinline__ unsigned long long wave_max_u64(unsigned long long v) {
#pragma unroll
    for (int off = 32; off > 0; off >>= 1) {
        unsigned long long o = __shfl_xor(v, off, 64);
        v = (o > v) ? o : v;
    }
    return v;
}

// ---------------- Kernel 1: lf rows + gfT (fp16 in, f32 out) — proven v7 -----
__global__ __launch_bounds__(256)
void hp_feat_v8(const unsigned short* __restrict__ x,
                const unsigned short* __restrict__ Wl,
                const unsigned short* __restrict__ Wg,
                float* __restrict__ lf, float* __restrict__ gfT)
{
    __shared__ float xs[32][68];
    __shared__ float ws[32][68];
    __shared__ float trans[64][68];

    const int tid = threadIdx.x;
    const int half = blockIdx.x & 1;
    const long row0 = (long)(blockIdx.x >> 1) * 64;
    const unsigned short* W = half ? Wg : Wl;
    const int tx = tid & 15, ty = tid >> 4;

    float acc[4][4];
#pragma unroll
    for (int r = 0; r < 4; r++)
#pragma unroll
        for (int c = 0; c < 4; c++) acc[r][c] = 0.f;

    for (int k0 = 0; k0 < DMODEL; k0 += 32) {
        {
            int r = tid >> 2, c8 = (tid & 3) * 8;
            uint4 v = *(const uint4*)(x + (row0 + r) * DMODEL + k0 + c8);
            float2 f;
            f = h2f2(v.x); xs[c8 + 0][r] = f.x; xs[c8 + 1][r] = f.y;
            f = h2f2(v.y); xs[c8 + 2][r] = f.x; xs[c8 + 3][r] = f.y;
            f = h2f2(v.z); xs[c8 + 4][r] = f.x; xs[c8 + 5][r] = f.y;
            f = h2f2(v.w); xs[c8 + 6][r] = f.x; xs[c8 + 7][r] = f.y;
        }
        {
            int r = tid >> 2, c8 = (tid & 3) * 8;
            uint4 v = *(const uint4*)(W + (long)r * DMODEL + k0 + c8);
            float2 f;
            f = h2f2(v.x); ws[c8 + 0][r] = f.x; ws[c8 + 1][r] = f.y;
            f = h2f2(v.y); ws[c8 + 2][r] = f.x; ws[c8 + 3][r] = f.y;
            f = h2f2(v.z); ws[c8 + 4][r] = f.x; ws[c8 + 5][r] = f.y;
            f = h2f2(v.w); ws[c8 + 6][r] = f.x; ws[c8 + 7][r] = f.y;
        }
        __syncthreads();
#pragma unroll
        for (int kk = 0; kk < 32; kk++) {
            float4 a  = *(const float4*)&xs[kk][ty * 4];
            float4 bv = *(const float4*)&ws[kk][tx * 4];
            const float ar[4] = {a.x, a.y, a.z, a.w};
            const float bc[4] = {bv.x, bv.y, bv.z, bv.w};
#pragma unroll
            for (int r = 0; r < 4; r++)
#pragma unroll
                for (int c = 0; c < 4; c++)
                    acc[r][c] = fmaf(ar[r], bc[c], acc[r][c]);
        }
        __syncthreads();
    }

    if (!half) {
#pragma unroll
        for (int r = 0; r < 4; r++) {
            float4 st = make_float4(acc[r][0], acc[r][1], acc[r][2], acc[r][3]);
            *(float4*)(lf + (row0 + ty * 4 + r) * ID + tx * 4) = st;
        }
    } else {
#pragma unroll
        for (int r = 0; r < 4; r++)
#pragma unroll
            for (int c = 0; c < 4; c++)
                trans[tx * 4 + c][ty * 4 + r] = acc[r][c];
        __syncthreads();
        const int b = (int)(row0 >> 12), s0 = (int)(row0 & 4095);
        const int col = tid >> 2, rs = (tid & 3) * 16;
        float* dst = gfT + ((long)b * ID + col) * SEQ + s0 + rs;
#pragma unroll
        for (int u = 0; u < 4; u++)
            *(float4*)(dst + 4 * u) = *(const float4*)&trans[col][rs + 4 * u];
    }
}

// ---------------- Kernel 2: TQ=4 queries per block ---------------------------
// Mapping: b=(bid>>1)&3, qg=(bid>>3)*2|(bid&1) -> bid%8 = 2b+parity, so each
// XCD only ever touches one batch's gfT (1MiB, L2-resident).
// Phase 1: outer-product scores in registers (v7, proven).
// Phase 2: per-wave top-32 via shuffle extract-max on packed u64
// (bits(relu(s))+1)<<13 | (SEQ-k) — u64 order = value desc, index asc = JAX
// tie order. No barriers. Then ONE barrier; wave w merges query w's 4x32
// candidates (top-32 of union = global top-32; selection is a set).
__global__ __launch_bounds__(256)
void hp_mask_v8(const float* __restrict__ lf, const float* __restrict__ gfT,
                unsigned short* __restrict__ out)
{
    __shared__ float qv[TQ][ID];
    __shared__ float lq[TQ][ID];
    __shared__ unsigned long long cand[TQ][4][GK];   // 4 KiB
    __shared__ int   sel[TQ][GK];
    __shared__ int   lsel[TQ][4];
    __shared__ int   lcnt[TQ];
    __shared__ float lsc[TQ][LW];

    const int tid = threadIdx.x;
    const int lane = tid & 63, w = tid >> 6;
    const int bid = blockIdx.x;
    const int b = (bid >> 1) & 3;                    // XCD-pinned
    const int q0 = (((bid >> 3) << 1) | (bid & 1)) * TQ;
    const float* gTb = gfT + (long)b * ID * SEQ;
    const float* lfb = lf + (long)b * SEQ * ID;

    {
        int d = tid >> 2, qi = tid & 3;
        qv[qi][d] = gTb[(long)d * SEQ + q0 + qi];
        int qi2 = tid >> 6, d2 = tid & 63;
        lq[qi2][d2] = lfb[(long)(q0 + qi2) * ID + d2];
    }
    __syncthreads();

    // ---- Phase 1: register-resident scores ----------------------------------
    float acc[4][4][TQ];                  // [c][j][qi]
#pragma unroll
    for (int c = 0; c < 4; c++)
#pragma unroll
        for (int j = 0; j < 4; j++)
#pragma unroll
            for (int qi = 0; qi < TQ; qi++) acc[c][j][qi] = 0.f;

    for (int d = 0; d < ID; d++) {
        float qd[TQ];
#pragma unroll
        for (int qi = 0; qi < TQ; qi++) qd[qi] = qv[qi][d];
        const float4* rowp = (const float4*)(gTb + (long)d * SEQ);
#pragma unroll
        for (int c = 0; c < 4; c++) {
            float4 kv = rowp[c * 256 + tid];
#pragma unroll
            for (int qi = 0; qi < TQ; qi++) {
                acc[c][0][qi] = fmaf(kv.x, qd[qi], acc[c][0][qi]);
                acc[c][1][qi] = fmaf(kv.y, qd[qi], acc[c][1][qi]);
                acc[c][2][qi] = fmaf(kv.z, qd[qi], acc[c][2][qi]);
                acc[c][3][qi] = fmaf(kv.w, qd[qi], acc[c][3][qi]);
            }
        }
    }

    // ---- Phase 2a: per-wave top-32 per query (barrier-free) -----------------
#pragma unroll 1
    for (int qi = 0; qi < TQ; qi++) {
        const int q = q0 + qi;
        unsigned long long packed[16];
#pragma unroll
        for (int c = 0; c < 4; c++)
#pragma unroll
            for (int j = 0; j < 4; j++) {
                int k = 1024 * c + 4 * tid + j;
                float sv = acc[c][j][qi];
                bool banned = (k <= q) && (k >= q - (LW - 1));
                unsigned int u = banned ? 0u
                               : (__float_as_uint(fmaxf(sv, 0.f)) + 1u);
                packed[c * 4 + j] = ((unsigned long long)u << 13)
                                  | (unsigned long long)(SEQ - k);
            }
        unsigned long long bestp = 0ull;
#pragma unroll
        for (int i = 0; i < 16; i++) bestp = packed[i] > bestp ? packed[i] : bestp;

#pragma unroll 1
        for (int it = 0; it < GK; it++) {
            unsigned long long m = wave_max_u64(bestp);
            if (bestp == m) {                    // unique owner lane
#pragma unroll
                for (int i = 0; i < 16; i++) if (packed[i] == m) packed[i] = 0ull;
                bestp = 0ull;
#pragma unroll
                for (int i = 0; i < 16; i++)
                    bestp = packed[i] > bestp ? packed[i] : bestp;
            }
            if (lane == 0) cand[qi][w][it] = m;
        }
    }
    __syncthreads();

    // ---- Phase 2b: wave w merges query w's 128 candidates -------------------
    {
        const unsigned long long* cf = &cand[w][0][0];   // 128 contiguous
        unsigned long long c0 = cf[lane], c1 = cf[64 + lane];
#pragma unroll 1
        for (int it = 0; it < GK; it++) {
            unsigned long long pm = (c0 > c1) ? c0 : c1;
            unsigned long long m = wave_max_u64(pm);
            if (c0 == m) c0 = 0ull;
            else if (c1 == m) c1 = 0ull;
            if (lane == 0) sel[w][it] = SEQ - (int)(m & 0x1FFFull);
        }
    }

    // ---- local window: 16 scores per query, stable top-ks -------------------
    if (tid < TQ * LW) {
        int qi = tid >> 4, wnd = tid & 15;
        int q = q0 + qi;
        int win = q - (LW - 1) + wnd;
        float v = NEG_INF;
        if (win >= 0) {
            const float4* kr = (const float4*)(lfb + (long)win * ID);
            float s = 0.f;
#pragma unroll
            for (int d = 0; d < 16; d++) {
                float4 kvv = kr[d];
                const float4 qd = *(const float4*)&lq[qi][d * 4];
                s = fmaf(kvv.x, qd.x, s); s = fmaf(kvv.y, qd.y, s);
                s = fmaf(kvv.z, qd.z, s); s = fmaf(kvv.w, qd.w, s);
            }
            v = fmaxf(s, 0.f);
        }
        lsc[qi][wnd] = v;
    }
    __syncthreads();
    if (tid < TQ) {
        int qi = tid, q = q0 + qi;
        int L = (q + 1 < LW) ? q + 1 : LW;
        int ks = L / 5; if (ks < 1) ks = 1;   // == max(1, int(L*0.2))
        lcnt[qi] = ks;
        for (int t = 0; t < ks; t++) {
            float best = NEG_INF; int bi = 0;
            for (int wnd = 0; wnd < LW; wnd++) {
                float v = lsc[qi][wnd];
                if (v > best) { best = v; bi = wnd; }  // strict > keeps lowest idx
            }
            lsc[qi][bi] = NEG_INF;
            lsel[qi][t] = q - (LW - 1) + bi;
        }
    }
    __syncthreads();

    // ---- output: bulk MASKED rows, then scatter zeros -----------------------
    uint4* orow = (uint4*)(out + ((long)b * SEQ + q0) * SEQ);
    const uint4 m4 = make_uint4(MASKED4, MASKED4, MASKED4, MASKED4);
#pragma unroll
    for (int i = 0; i < TQ * SEQ / 8 / 256; i++)   // 8 iters
        orow[i * 256 + tid] = m4;
    __syncthreads();                                // order bulk before scatter
    if (tid < TQ * GK) {                            // 128 global zeros
        int qi = tid >> 5;
        out[((long)b * SEQ + q0 + qi) * SEQ + sel[qi][tid & 31]] = 0;
    } else if (tid < TQ * GK + TQ * 4) {            // <=12 local zeros
        int t = tid - TQ * GK;
        int qi = t >> 2, j = t & 3;
        if (j < lcnt[qi])
            out[((long)b * SEQ + q0 + qi) * SEQ + lsel[qi][j]] = 0;
    }
}

extern "C" void kernel_launch(void* const* d_in, const int* in_sizes, int n_in,
                              void* d_out, int out_size, void* d_ws, size_t ws_size,
                              hipStream_t stream) {
    const unsigned short* x  = (const unsigned short*)d_in[0];
    const unsigned short* Wl = (const unsigned short*)d_in[1];
    // d_in[2] = W_medium: dead in the reference — skipped.
    const unsigned short* Wg = (const unsigned short*)d_in[3];
    unsigned short* out = (unsigned short*)d_out;

    float* lf  = (float*)d_ws;                        // 4 MiB, row-major
    float* gfT = lf + (long)NB * SEQ * ID;            // 4 MiB, [b][d][k]

    hp_feat_v8<<<(NB * SEQ / 64) * 2, 256, 0, stream>>>(x, Wl, Wg, lf, gfT);
    hp_mask_v8<<<NB * SEQ / TQ, 256, 0, stream>>>(lf, gfT, out);
}